// Round 11
// baseline (278.885 us; speedup 1.0000x reference)
//
#include <hip/hip_runtime.h>

typedef unsigned int uint;
typedef unsigned short ushort;

typedef __bf16 bf16x8 __attribute__((ext_vector_type(8)));
typedef float f32x4 __attribute__((ext_vector_type(4)));

#define CAP 48    // per-dst bucket capacity; max in-degree ~35 (P(>=48) < 1e-8)
#define RSTR 136  // epilogue repack row stride (ushorts): 272 B, 16B-aligned, bank-spread

// ---------- helpers ----------
__device__ __forceinline__ float bf2f(ushort u) {
    return __uint_as_float(((uint)u) << 16);
}
__device__ __forceinline__ ushort f2bf(float f) {
    uint u = __float_as_uint(f);
    u += 0x7fffu + ((u >> 16) & 1u);   // round-to-nearest-even
    return (ushort)(u >> 16);
}
__device__ __forceinline__ void load_lds16(const ushort* g, ushort* l) {
    __builtin_amdgcn_global_load_lds(
        (const __attribute__((address_space(1))) void*)g,
        (__attribute__((address_space(3))) void*)l, 16, 0, 0);
}
__device__ __forceinline__ int swz(int row) { return (row + (row >> 2)) & 3; }

// DPP butterfly add (VALU-only, no LGKM): ctrl must be compile-time constant
template<int CTRL>
__device__ __forceinline__ float dppadd(float p) {
    int t = __builtin_amdgcn_update_dpp(0, __float_as_int(p), CTRL, 0xf, 0xf, true);
    return p + __int_as_float(t);
}

// ---------- fused prep: convert X, convert W (x4), CSR cnt init (both hops) ----------
__global__ __launch_bounds__(256) void prep(
    const float* __restrict__ X, ushort* __restrict__ Xb, int Nrows, int Mpad,
    const float* __restrict__ Wl0, const float* __restrict__ Wr0,
    const float* __restrict__ Wl1, const float* __restrict__ Wr1,
    ushort* __restrict__ Wt,
    int* __restrict__ cnt0, int* __restrict__ cnt1)
{
    const int BX = Mpad / 8;                  // convert_x blocks
    int blk = blockIdx.x;
    if (blk < BX) {
        int i = blk * 256 + threadIdx.x;
        int base = i * 8;
        int row = base >> 8;
        ushort o[8];
        if (row < Nrows) {
            float4 v0 = *(const float4*)(X + base);
            float4 v1 = *(const float4*)(X + base + 4);
            o[0] = f2bf(v0.x); o[1] = f2bf(v0.y); o[2] = f2bf(v0.z); o[3] = f2bf(v0.w);
            o[4] = f2bf(v1.x); o[5] = f2bf(v1.y); o[6] = f2bf(v1.z); o[7] = f2bf(v1.w);
        } else {
#pragma unroll
            for (int j = 0; j < 8; j++) o[j] = 0;
        }
        *(uint4*)(Xb + base) = *(const uint4*)o;
        return;
    }
    blk -= BX;
    if (blk < 1024) {
        int n = blk;
        int k = threadIdx.x;
        const float* W = (n < 256) ? Wl0 : (n < 512) ? Wr0 : (n < 768) ? Wl1 : Wr1;
        Wt[n * 256 + k] = f2bf(W[k * 256 + (n & 255)]);
        return;
    }
    blk -= 1024;
    int d = blk * 256 + threadIdx.x;
    if (d < Nrows) {
        cnt0[d] = 0;     // self loop handled inline in gat kernel
        cnt1[d] = 0;
    }
}

// ---------- standalone CSR scatter (fallback path only) ----------
__global__ __launch_bounds__(256) void csr_scatter2(
    const int* __restrict__ ei1, const int* __restrict__ ei2,
    int* __restrict__ cnt0, int* __restrict__ srcs0,
    int* __restrict__ cnt1, int* __restrict__ srcs1,
    int E1, int E2)
{
    int e = blockIdx.x * 256 + threadIdx.x;
    if (e < E1) {
        int d = ei1[E1 + e];
        int pos = atomicAdd(&cnt0[d], 1);
        if (pos < CAP) srcs0[(size_t)d * CAP + pos] = ei1[e];
    } else if (e < E1 + E2) {
        int e2 = e - E1;
        int d = ei2[E2 + e2];
        int pos = atomicAdd(&cnt1[d], 1);
        if (pos < CAP) srcs1[(size_t)d * CAP + pos] = ei2[e2];
    }
}

// ---------- GEMM + CSR scatter in ONE dispatch ----------
// blocks [0, SB): edge scatter (launched first -> overlaps gemm tiles)
// blocks [SB, SB+GT): MFMA gemm tiles, n-fastest (blk-SB): bx=&7 n-tile, >>3 m-tile
__global__ __launch_bounds__(256, 2) void gemm_plus(
    const ushort* __restrict__ Xb,
    const ushort* __restrict__ Wt,
    ushort* __restrict__ XP,
    int Nrows, int SB,
    const int* __restrict__ ei1, const int* __restrict__ ei2,
    int* __restrict__ cnt0, int* __restrict__ srcs0,
    int* __restrict__ cnt1, int* __restrict__ srcs1,
    int E1, int E2)
{
    __shared__ ushort SH[64 * RSTR];   // K-loop: As=SH[0:4096], Bs=SH[4096:8192]

    if ((int)blockIdx.x < SB) {
        int e = blockIdx.x * 256 + threadIdx.x;
        if (e < E1) {
            int d = ei1[E1 + e];
            int pos = atomicAdd(&cnt0[d], 1);
            if (pos < CAP) srcs0[(size_t)d * CAP + pos] = ei1[e];
        } else if (e < E1 + E2) {
            int e2 = e - E1;
            int d = ei2[E2 + e2];
            int pos = atomicAdd(&cnt1[d], 1);
            if (pos < CAP) srcs1[(size_t)d * CAP + pos] = ei2[e2];
        }
        return;
    }

    ushort* As = SH;
    ushort* Bs = SH + 128 * 32;

    const int tid = threadIdx.x;
    const int w = tid >> 6, l = tid & 63;
    const int wm = w & 1, wn = w >> 1;
    const int gblk = blockIdx.x - SB;
    const int m0 = (gblk >> 3) * 128;
    const int n0g = (gblk & 7) * 128;

    f32x4 acc[4][4];
#pragma unroll
    for (int i = 0; i < 4; i++)
#pragma unroll
        for (int j = 0; j < 4; j++) acc[i][j] = (f32x4)(0.f);

    const int fr = l & 15, fq = l >> 4;
    int a_off[4], b_off[4];
#pragma unroll
    for (int t = 0; t < 4; t++) {
        int rA = wm * 64 + t * 16 + fr;
        a_off[t] = (rA * 4 + ((fq + swz(rA)) & 3)) * 8;
        int rB = wn * 64 + t * 16 + fr;
        b_off[t] = (rB * 4 + ((fq + swz(rB)) & 3)) * 8;
    }

    for (int k0 = 0; k0 < 256; k0 += 32) {
        __syncthreads();
#pragma unroll
        for (int r = 0; r < 2; r++) {
            int slot = r * 256 + tid;
            int row = slot >> 2;
            int kp = ((slot & 3) - swz(row)) & 3;
            load_lds16(Xb + (size_t)(m0 + row) * 256 + k0 + kp * 8,
                       &As[(r * 256 + w * 64) * 8]);
            load_lds16(Wt + (size_t)(n0g + row) * 256 + k0 + kp * 8,
                       &Bs[(r * 256 + w * 64) * 8]);
        }
        __syncthreads();

        bf16x8 a[4], b[4];
#pragma unroll
        for (int t = 0; t < 4; t++) {
            a[t] = *(const bf16x8*)(As + a_off[t]);
            b[t] = *(const bf16x8*)(Bs + b_off[t]);
        }
#pragma unroll
        for (int mi = 0; mi < 4; mi++)
#pragma unroll
            for (int ni = 0; ni < 4; ni++)
                acc[mi][ni] = __builtin_amdgcn_mfma_f32_16x16x32_bf16(
                    a[mi], b[ni], acc[mi][ni], 0, 0, 0);
    }

    // ---- epilogue: LDS repack -> coalesced dwordx4 stores (2 rounds of 64 rows) ----
    ushort* OUT = XP + (size_t)(n0g >> 8) * ((size_t)Nrows * 256);
    const int colbase = n0g & 255;
    const int cb = wn * 64 + fr;
#pragma unroll
    for (int r = 0; r < 2; r++) {
        __syncthreads();
#pragma unroll
        for (int mm = 0; mm < 2; mm++) {
            int mi = 2 * r + mm;
            int brb = (wm * 32 + mm * 16 + fq * 4) * RSTR + cb;
#pragma unroll
            for (int reg = 0; reg < 4; reg++)
#pragma unroll
                for (int ni = 0; ni < 4; ni++)
                    SH[brb + reg * RSTR + ni * 16] = f2bf(acc[mi][ni][reg]);
        }
        __syncthreads();
        int br = tid >> 2;
        int grow = m0 + (br >> 5) * 64 + (2 * r + ((br >> 4) & 1)) * 16 + (br & 15);
        bool ok = (grow < Nrows);
        int cc = (tid & 3) * 8;
#pragma unroll
        for (int q = 0; q < 4; q++) {
            uint4 v = *(const uint4*)(SH + br * RSTR + cc + q * 32);
            if (ok) *(uint4*)(OUT + (size_t)grow * 256 + colbase + cc + q * 32) = v;
        }
    }
}

// ---------- fused GAT aggregation: 2 edges/wave, 8 ch/lane, DPP score reduce ----------
// lane = hl*32 + sub; hl = edge-half (A/B), sub -> head h=sub>>3, q=sub&7,
// channels h*64+q*8 .. +7 (byte offset sub*16 within a 512 B row)

__device__ __forceinline__ uint4 pair_load(const ushort* __restrict__ XL, int sv,
                                           int e, int cp, uint hl, uint sub16)
{
    int eA = (e     < cp) ? e     : cp;
    int eB = (e + 1 < cp) ? e + 1 : cp;
    uint sA = (uint)__builtin_amdgcn_readlane(sv, eA) * 512u;   // SGPR
    uint sB = (uint)__builtin_amdgcn_readlane(sv, eB) * 512u;   // SGPR
    uint off = sA + hl * (sB - sA) + sub16;                     // half-select
    return *(const uint4*)((const char*)XL + off);
}

__device__ __forceinline__ void eaccp(uint4 raw, int deadB, uint hl,
    const float* __restrict__ xr8, const float* __restrict__ av,
    float* __restrict__ acc, float& den)
{
    float x[8];
    x[0] = __uint_as_float(raw.x << 16);
    x[1] = __uint_as_float(raw.x & 0xffff0000u);
    x[2] = __uint_as_float(raw.y << 16);
    x[3] = __uint_as_float(raw.y & 0xffff0000u);
    x[4] = __uint_as_float(raw.z << 16);
    x[5] = __uint_as_float(raw.z & 0xffff0000u);
    x[6] = __uint_as_float(raw.w << 16);
    x[7] = __uint_as_float(raw.w & 0xffff0000u);
    float p0 = 0.f, p1 = 0.f;          // two chains halve serial FMA latency
#pragma unroll
    for (int j = 0; j < 4; j++) {
        float t = x[j] + xr8[j];
        float lr = fmaxf(t, 0.2f * t);
        p0 = fmaf(av[j], lr, p0);
    }
#pragma unroll
    for (int j = 4; j < 8; j++) {
        float t = x[j] + xr8[j];
        float lr = fmaxf(t, 0.2f * t);
        p1 = fmaf(av[j], lr, p1);
    }
    float p = p0 + p1;
    p = dppadd<0xB1>(p);    // xor1 (quad_perm [1,0,3,2])
    p = dppadd<0x4E>(p);    // xor2 (quad_perm [2,3,0,1])
    p = dppadd<0x141>(p);   // xor7 (row_half_mirror) -> sum over 8-lane head group
    float pe = __expf(p);
    if (deadB & (int)hl) pe = 0.f;
    den += pe;
#pragma unroll
    for (int j = 0; j < 8; j++) acc[j] = fmaf(pe, x[j], acc[j]);
}

__device__ __forceinline__ void gat_hop(
    const ushort* __restrict__ XL, const ushort* __restrict__ XR,
    const float* __restrict__ att, const int* __restrict__ cnt,
    const int* __restrict__ srcs, int self, int d, int lane,
    uint hl, uint sub, uint sub16,
    float* __restrict__ acc, float& den)
{
    uint4 xrr = *(const uint4*)((const char*)XR + (uint)d * 512u + sub16);
    float xr8[8];
    xr8[0] = __uint_as_float(xrr.x << 16);
    xr8[1] = __uint_as_float(xrr.x & 0xffff0000u);
    xr8[2] = __uint_as_float(xrr.y << 16);
    xr8[3] = __uint_as_float(xrr.y & 0xffff0000u);
    xr8[4] = __uint_as_float(xrr.z << 16);
    xr8[5] = __uint_as_float(xrr.z & 0xffff0000u);
    xr8[6] = __uint_as_float(xrr.w << 16);
    xr8[7] = __uint_as_float(xrr.w & 0xffff0000u);
    float av[8];
    *(float4*)(av)     = *(const float4*)(att + sub * 8);
    *(float4*)(av + 4) = *(const float4*)(att + sub * 8 + 4);

#pragma unroll
    for (int j = 0; j < 8; j++) acc[j] = 0.f;
    den = 0.f;

    int m = __builtin_amdgcn_readfirstlane(cnt[d]);   // SGPR
    if (m > CAP) m = CAP;
    const int mt = m + self;                          // virtual edges (incl. self)
    if (mt <= 0) return;

    // per-lane virtual edge src table (readlane-broadcast inside the loop)
    int idx = lane - self;
    int mm1 = (m > 0) ? (m - 1) : 0;
    int slot = idx < 0 ? 0 : (idx > mm1 ? mm1 : idx);
    int sv = srcs[(size_t)d * CAP + slot];
    if (self && lane == 0) sv = d;

    const int cp = mt - 1;
    uint4 pf0 = pair_load(XL, sv, 0, cp, hl, sub16);
    uint4 pf1 = pair_load(XL, sv, 2, cp, hl, sub16);
    for (int i = 0; i < mt; i += 4) {
        uint4 c0 = pf0, c1 = pf1;
        pf0 = pair_load(XL, sv, i + 4, cp, hl, sub16);   // branch-free clamped
        pf1 = pair_load(XL, sv, i + 6, cp, hl, sub16);
        eaccp(c0, (i + 1 >= mt) ? 1 : 0, hl, xr8, av, acc, den);
        if (i + 2 < mt)
            eaccp(c1, (i + 3 >= mt) ? 1 : 0, hl, xr8, av, acc, den);
    }
}

__global__ __launch_bounds__(256) void gat_fused(
    const ushort* __restrict__ XL0, const ushort* __restrict__ XR0,
    const float* __restrict__ att0,
    const int* __restrict__ cnt0, const int* __restrict__ srcs0,
    int self0, float scale0,
    const ushort* __restrict__ XL1, const ushort* __restrict__ XR1,
    const float* __restrict__ att1,
    const int* __restrict__ cnt1, const int* __restrict__ srcs1,
    float scale1,
    const float* __restrict__ base, float* __restrict__ outp, int N)
{
    int d = blockIdx.x * 4 + (threadIdx.x >> 6);
    if (d >= N) return;
    int lane = threadIdx.x & 63;
    uint hl = (uint)(lane >> 5);
    uint sub = (uint)(lane & 31);
    uint sub16 = sub * 16u;

    float acc0[8], den0;
    gat_hop(XL0, XR0, att0, cnt0, srcs0, self0, d, lane, hl, sub, sub16, acc0, den0);

    float v[8];
    den0 += __shfl_xor(den0, 32);
    float s0 = scale0 / (den0 + 1e-16f);
    if (cnt1) {
        float acc1[8], den1;
        gat_hop(XL1, XR1, att1, cnt1, srcs1, 0, d, lane, hl, sub, sub16, acc1, den1);
        den1 += __shfl_xor(den1, 32);
        float s1 = scale1 / (den1 + 1e-16f);
#pragma unroll
        for (int j = 0; j < 8; j++) v[j] = acc0[j] * s0 + acc1[j] * s1;
    } else {
#pragma unroll
        for (int j = 0; j < 8; j++) v[j] = acc0[j] * s0;
    }
    // sum over 4 heads (xor 8,16) and the 2 edge-halves (xor 32)
#pragma unroll
    for (int j = 0; j < 8; j++) {
        v[j] += __shfl_xor(v[j], 8);
        v[j] += __shfl_xor(v[j], 16);
        v[j] += __shfl_xor(v[j], 32);
    }
    if (lane < 8) {
        float* dst = outp + (size_t)d * 64 + lane * 8;
        float4 w0 = {v[0], v[1], v[2], v[3]};
        float4 w1 = {v[4], v[5], v[6], v[7]};
        if (base) {
            float4 b0 = *(const float4*)(base + (size_t)d * 64 + lane * 8);
            float4 b1 = *(const float4*)(base + (size_t)d * 64 + lane * 8 + 4);
            w0.x += b0.x; w0.y += b0.y; w0.z += b0.z; w0.w += b0.w;
            w1.x += b1.x; w1.y += b1.y; w1.z += b1.z; w1.w += b1.w;
        }
        *(float4*)dst = w0;
        *(float4*)(dst + 4) = w1;
    }
}

// ---------- launch ----------
extern "C" void kernel_launch(void* const* d_in, const int* in_sizes, int n_in,
                              void* d_out, int out_size, void* d_ws, size_t ws_size,
                              hipStream_t stream)
{
    const float* x    = (const float*)d_in[0];
    const float* Wl0  = (const float*)d_in[1];
    const float* Wr0  = (const float*)d_in[2];
    const float* att0 = (const float*)d_in[3];
    const float* Wl1  = (const float*)d_in[4];
    const float* Wr1  = (const float*)d_in[5];
    const float* att1 = (const float*)d_in[6];
    const int* ei1 = (const int*)d_in[7];
    const int* ei2 = (const int*)d_in[8];

    const int N  = in_sizes[0] / 256;
    const int E1 = in_sizes[7] / 2;
    const int E2 = in_sizes[8] / 2;
    const int Mpad = ((N + 127) / 128) * 128;
    const size_t NB = (size_t)N * 256;

    // workspace layout
    char* ws = (char*)d_ws;
    size_t off = 0;
    ushort* Xb  = (ushort*)(ws + off); off += (size_t)Mpad * 256 * sizeof(ushort);
    ushort* Wt  = (ushort*)(ws + off); off += (size_t)1024 * 256 * sizeof(ushort);
    int* cnt0   = (int*)(ws + off);    off += (size_t)N * sizeof(int);
    int* cnt1   = (int*)(ws + off);    off += (size_t)N * sizeof(int);
    int* srcs0  = (int*)(ws + off);    off += (size_t)N * CAP * sizeof(int);
    int* srcs1  = (int*)(ws + off);    off += (size_t)N * CAP * sizeof(int);
    ushort* XP  = (ushort*)(ws + off);
    size_t need_mega = off + 4 * NB * sizeof(ushort);   // ~148 MB
    const bool mega = (ws_size >= need_mega);
    float* outf = (float*)d_out;

    const int BX = Mpad / 8;
    int prep_blocks = BX + 1024 + (N + 255) / 256;
    prep<<<prep_blocks, 256, 0, stream>>>(x, Xb, N, Mpad, Wl0, Wr0, Wl1, Wr1,
                                          Wt, cnt0, cnt1);

    const int SB = (E1 + E2 + 255) / 256;
    int aggblk = (N + 3) / 4;
    if (mega) {
        // 3-dispatch DAG: prep -> (scatter||gemm) -> aggregate
        const int GT = 8 * (Mpad / 128);
        gemm_plus<<<SB + GT, 256, 0, stream>>>(
            Xb, Wt, XP, N, SB,
            ei1, ei2, cnt0, srcs0, cnt1, srcs1, E1, E2);
        gat_fused<<<aggblk, 256, 0, stream>>>(
            XP, XP + NB, att0, cnt0, srcs0, 1, 0.25f,
            XP + 2 * NB, XP + 3 * NB, att1, cnt1, srcs1, 0.125f,
            nullptr, outf, N);
    } else {
        csr_scatter2<<<SB, 256, 0, stream>>>(
            ei1, ei2, cnt0, srcs0, cnt1, srcs1, E1, E2);
        const int GT = 4 * (Mpad / 128);
        gemm_plus<<<GT, 256, 0, stream>>>(
            Xb, Wt, XP, N, 0,
            ei1, ei2, cnt0, srcs0, cnt1, srcs1, 0, 0);
        gat_fused<<<aggblk, 256, 0, stream>>>(
            XP, XP + NB, att0, cnt0, srcs0, 1, 0.25f,
            nullptr, nullptr, nullptr, nullptr, nullptr, 0.f,
            nullptr, outf, N);
        gemm_plus<<<GT, 256, 0, stream>>>(
            Xb, Wt + 512 * 256, XP, N, 0,
            ei1, ei2, cnt0, srcs0, cnt1, srcs1, 0, 0);
        gat_fused<<<aggblk, 256, 0, stream>>>(
            XP, XP + NB, att1, cnt1, srcs1, 0, 0.125f,
            nullptr, nullptr, nullptr, nullptr, nullptr, 0.f,
            outf, outf, N);
    }
}

// Round 12
// 268.987 us; speedup vs baseline: 1.0368x; 1.0368x over previous
//
#include <hip/hip_runtime.h>

typedef unsigned int uint;
typedef unsigned short ushort;

typedef __bf16 bf16x8 __attribute__((ext_vector_type(8)));
typedef float f32x4 __attribute__((ext_vector_type(4)));

#define CAP 48    // per-dst bucket capacity; max in-degree ~35 (P(>=48) < 1e-8)
#define RSTR 136  // epilogue repack row stride (ushorts): 272 B, 16B-aligned, bank-spread

// ---------- helpers ----------
__device__ __forceinline__ float bf2f(ushort u) {
    return __uint_as_float(((uint)u) << 16);
}
__device__ __forceinline__ ushort f2bf(float f) {
    uint u = __float_as_uint(f);
    u += 0x7fffu + ((u >> 16) & 1u);   // round-to-nearest-even
    return (ushort)(u >> 16);
}
__device__ __forceinline__ void load_lds16(const ushort* g, ushort* l) {
    __builtin_amdgcn_global_load_lds(
        (const __attribute__((address_space(1))) void*)g,
        (__attribute__((address_space(3))) void*)l, 16, 0, 0);
}

// DPP butterfly add (VALU-only, no LGKM): ctrl must be compile-time constant
template<int CTRL>
__device__ __forceinline__ float dppadd(float p) {
    int t = __builtin_amdgcn_update_dpp(0, __float_as_int(p), CTRL, 0xf, 0xf, true);
    return p + __int_as_float(t);
}

// ---------- fused prep: convert X, convert W (x4), CSR cnt init (both hops) ----------
__global__ __launch_bounds__(256) void prep(
    const float* __restrict__ X, ushort* __restrict__ Xb, int Nrows, int Mpad,
    const float* __restrict__ Wl0, const float* __restrict__ Wr0,
    const float* __restrict__ Wl1, const float* __restrict__ Wr1,
    ushort* __restrict__ Wt,
    int* __restrict__ cnt0, int* __restrict__ cnt1)
{
    const int BX = Mpad / 8;                  // convert_x blocks
    int blk = blockIdx.x;
    if (blk < BX) {
        int i = blk * 256 + threadIdx.x;
        int base = i * 8;
        int row = base >> 8;
        ushort o[8];
        if (row < Nrows) {
            float4 v0 = *(const float4*)(X + base);
            float4 v1 = *(const float4*)(X + base + 4);
            o[0] = f2bf(v0.x); o[1] = f2bf(v0.y); o[2] = f2bf(v0.z); o[3] = f2bf(v0.w);
            o[4] = f2bf(v1.x); o[5] = f2bf(v1.y); o[6] = f2bf(v1.z); o[7] = f2bf(v1.w);
        } else {
#pragma unroll
            for (int j = 0; j < 8; j++) o[j] = 0;
        }
        *(uint4*)(Xb + base) = *(const uint4*)o;
        return;
    }
    blk -= BX;
    if (blk < 1024) {
        int n = blk;
        int k = threadIdx.x;
        const float* W = (n < 256) ? Wl0 : (n < 512) ? Wr0 : (n < 768) ? Wl1 : Wr1;
        Wt[n * 256 + k] = f2bf(W[k * 256 + (n & 255)]);
        return;
    }
    blk -= 1024;
    int d = blk * 256 + threadIdx.x;
    if (d < Nrows) {
        cnt0[d] = 0;     // self loop handled inline in gat kernel
        cnt1[d] = 0;
    }
}

// ---------- CSR scatter, both graphs in one dispatch ----------
__global__ __launch_bounds__(256) void csr_scatter2(
    const int* __restrict__ ei1, const int* __restrict__ ei2,
    int* __restrict__ cnt0, int* __restrict__ srcs0,
    int* __restrict__ cnt1, int* __restrict__ srcs1,
    int E1, int E2)
{
    int e = blockIdx.x * 256 + threadIdx.x;
    if (e < E1) {
        int d = ei1[E1 + e];
        int pos = atomicAdd(&cnt0[d], 1);
        if (pos < CAP) srcs0[(size_t)d * CAP + pos] = ei1[e];
    } else if (e < E1 + E2) {
        int e2 = e - E1;
        int d = ei2[E2 + e2];
        int pos = atomicAdd(&cnt1[d], 1);
        if (pos < CAP) srcs1[(size_t)d * CAP + pos] = ei2[e2];
    }
}

// ---------- MFMA GEMM, BK=64: XP = Xb[Mpad,256] @ Wt^T (Wt n-major) ----------
// LDS layout: row r (0..127), chunk c (0..7, 16 B each, k-range c*8..c*8+7):
//   slot = r*8 + ((c + r) & 7)   -> fragment ds_read_b128 <=2-way conflict
// staging inverse: slot s -> row s>>3, chunk ((s&7) - row) & 7
__global__ __launch_bounds__(256, 2) void gemm_mfma(
    const ushort* __restrict__ Xb,
    const ushort* __restrict__ Wt,
    ushort* __restrict__ XP,
    int Nrows)
{
    __shared__ ushort SH[2 * 128 * 64];   // 32 KB: As [0:8192), Bs [8192:16384)
    ushort* As = SH;
    ushort* Bs = SH + 128 * 64;

    const int tid = threadIdx.x;
    const int w = tid >> 6, l = tid & 63;
    const int wm = w & 1, wn = w >> 1;
    const int m0 = blockIdx.y * 128;
    const int n0g = blockIdx.x * 128;

    f32x4 acc[4][4];
#pragma unroll
    for (int i = 0; i < 4; i++)
#pragma unroll
        for (int j = 0; j < 4; j++) acc[i][j] = (f32x4)(0.f);

    const int fr = l & 15, fq = l >> 4;
    int a_off[2][4], b_off[2][4];
#pragma unroll
    for (int g = 0; g < 2; g++)
#pragma unroll
        for (int t = 0; t < 4; t++) {
            int c = g * 4 + fq;
            int rA = wm * 64 + t * 16 + fr;
            a_off[g][t] = (rA * 8 + ((c + rA) & 7)) * 8;
            int rB = wn * 64 + t * 16 + fr;
            b_off[g][t] = (rB * 8 + ((c + rB) & 7)) * 8;
        }

    for (int k0 = 0; k0 < 256; k0 += 64) {
        __syncthreads();
#pragma unroll
        for (int rnd = 0; rnd < 4; rnd++) {
            int slot = rnd * 256 + tid;
            int row = slot >> 3;
            int c = ((slot & 7) - row) & 7;
            load_lds16(Xb + (size_t)(m0 + row) * 256 + k0 + c * 8,
                       &As[(rnd * 256 + w * 64) * 8]);
            load_lds16(Wt + (size_t)(n0g + row) * 256 + k0 + c * 8,
                       &Bs[(rnd * 256 + w * 64) * 8]);
        }
        __syncthreads();

#pragma unroll
        for (int g = 0; g < 2; g++) {
            bf16x8 a[4], b[4];
#pragma unroll
            for (int t = 0; t < 4; t++) {
                a[t] = *(const bf16x8*)(As + a_off[g][t]);
                b[t] = *(const bf16x8*)(Bs + b_off[g][t]);
            }
#pragma unroll
            for (int mi = 0; mi < 4; mi++)
#pragma unroll
                for (int ni = 0; ni < 4; ni++)
                    acc[mi][ni] = __builtin_amdgcn_mfma_f32_16x16x32_bf16(
                        a[mi], b[ni], acc[mi][ni], 0, 0, 0);
        }
    }

    // ---- epilogue: LDS repack -> coalesced dwordx4 stores (2 rounds of 64 rows) ----
    ushort* OUT = XP + (size_t)(n0g >> 8) * ((size_t)Nrows * 256);
    const int colbase = n0g & 255;
    const int cb = wn * 64 + fr;
#pragma unroll
    for (int r = 0; r < 2; r++) {
        __syncthreads();
#pragma unroll
        for (int mm = 0; mm < 2; mm++) {
            int mi = 2 * r + mm;
            int brb = (wm * 32 + mm * 16 + fq * 4) * RSTR + cb;
#pragma unroll
            for (int reg = 0; reg < 4; reg++)
#pragma unroll
                for (int ni = 0; ni < 4; ni++)
                    SH[brb + reg * RSTR + ni * 16] = f2bf(acc[mi][ni][reg]);
        }
        __syncthreads();
        int br = tid >> 2;
        int grow = m0 + (br >> 5) * 64 + (2 * r + ((br >> 4) & 1)) * 16 + (br & 15);
        bool ok = (grow < Nrows);
        int cc = (tid & 3) * 8;
#pragma unroll
        for (int q = 0; q < 4; q++) {
            uint4 v = *(const uint4*)(SH + br * RSTR + cc + q * 32);
            if (ok) *(uint4*)(OUT + (size_t)grow * 256 + colbase + cc + q * 32) = v;
        }
    }
}

// ---------- fused GAT aggregation: 2 edges/wave, 8 ch/lane, DPP score reduce ----------
__device__ __forceinline__ uint4 pair_load(const ushort* __restrict__ XL, int sv,
                                           int e, int cp, uint hl, uint sub16)
{
    int eA = (e     < cp) ? e     : cp;
    int eB = (e + 1 < cp) ? e + 1 : cp;
    uint sA = (uint)__builtin_amdgcn_readlane(sv, eA) * 512u;   // SGPR
    uint sB = (uint)__builtin_amdgcn_readlane(sv, eB) * 512u;   // SGPR
    uint off = sA + hl * (sB - sA) + sub16;                     // half-select
    return *(const uint4*)((const char*)XL + off);
}

__device__ __forceinline__ void eaccp(uint4 raw, int deadB, uint hl,
    const float* __restrict__ xr8, const float* __restrict__ av,
    float* __restrict__ acc, float& den)
{
    float x[8];
    x[0] = __uint_as_float(raw.x << 16);
    x[1] = __uint_as_float(raw.x & 0xffff0000u);
    x[2] = __uint_as_float(raw.y << 16);
    x[3] = __uint_as_float(raw.y & 0xffff0000u);
    x[4] = __uint_as_float(raw.z << 16);
    x[5] = __uint_as_float(raw.z & 0xffff0000u);
    x[6] = __uint_as_float(raw.w << 16);
    x[7] = __uint_as_float(raw.w & 0xffff0000u);
    float p0 = 0.f, p1 = 0.f;          // two chains halve serial FMA latency
#pragma unroll
    for (int j = 0; j < 4; j++) {
        float t = x[j] + xr8[j];
        float lr = fmaxf(t, 0.2f * t);
        p0 = fmaf(av[j], lr, p0);
    }
#pragma unroll
    for (int j = 4; j < 8; j++) {
        float t = x[j] + xr8[j];
        float lr = fmaxf(t, 0.2f * t);
        p1 = fmaf(av[j], lr, p1);
    }
    float p = p0 + p1;
    p = dppadd<0xB1>(p);    // xor1
    p = dppadd<0x4E>(p);    // xor2
    p = dppadd<0x141>(p);   // xor7 (row_half_mirror) -> 8-lane head group sum
    float pe = __expf(p);
    if (deadB & (int)hl) pe = 0.f;
    den += pe;
#pragma unroll
    for (int j = 0; j < 8; j++) acc[j] = fmaf(pe, x[j], acc[j]);
}

__device__ __forceinline__ void gat_hop(
    const ushort* __restrict__ XL, const ushort* __restrict__ XR,
    const float* __restrict__ att, const int* __restrict__ cnt,
    const int* __restrict__ srcs, int self, int d, int lane,
    uint hl, uint sub, uint sub16,
    float* __restrict__ acc, float& den)
{
    uint4 xrr = *(const uint4*)((const char*)XR + (uint)d * 512u + sub16);
    float xr8[8];
    xr8[0] = __uint_as_float(xrr.x << 16);
    xr8[1] = __uint_as_float(xrr.x & 0xffff0000u);
    xr8[2] = __uint_as_float(xrr.y << 16);
    xr8[3] = __uint_as_float(xrr.y & 0xffff0000u);
    xr8[4] = __uint_as_float(xrr.z << 16);
    xr8[5] = __uint_as_float(xrr.z & 0xffff0000u);
    xr8[6] = __uint_as_float(xrr.w << 16);
    xr8[7] = __uint_as_float(xrr.w & 0xffff0000u);
    float av[8];
    *(float4*)(av)     = *(const float4*)(att + sub * 8);
    *(float4*)(av + 4) = *(const float4*)(att + sub * 8 + 4);

#pragma unroll
    for (int j = 0; j < 8; j++) acc[j] = 0.f;
    den = 0.f;

    int m = __builtin_amdgcn_readfirstlane(cnt[d]);   // SGPR
    if (m > CAP) m = CAP;
    const int mt = m + self;                          // virtual edges (incl. self)
    if (mt <= 0) return;

    int idx = lane - self;
    int mm1 = (m > 0) ? (m - 1) : 0;
    int slot = idx < 0 ? 0 : (idx > mm1 ? mm1 : idx);
    int sv = srcs[(size_t)d * CAP + slot];
    if (self && lane == 0) sv = d;

    const int cp = mt - 1;
    uint4 pf0 = pair_load(XL, sv, 0, cp, hl, sub16);
    uint4 pf1 = pair_load(XL, sv, 2, cp, hl, sub16);
    for (int i = 0; i < mt; i += 4) {
        uint4 c0 = pf0, c1 = pf1;
        pf0 = pair_load(XL, sv, i + 4, cp, hl, sub16);   // branch-free clamped
        pf1 = pair_load(XL, sv, i + 6, cp, hl, sub16);
        eaccp(c0, (i + 1 >= mt) ? 1 : 0, hl, xr8, av, acc, den);
        if (i + 2 < mt)
            eaccp(c1, (i + 3 >= mt) ? 1 : 0, hl, xr8, av, acc, den);
    }
}

__global__ __launch_bounds__(256) void gat_fused(
    const ushort* __restrict__ XL0, const ushort* __restrict__ XR0,
    const float* __restrict__ att0,
    const int* __restrict__ cnt0, const int* __restrict__ srcs0,
    int self0, float scale0,
    const ushort* __restrict__ XL1, const ushort* __restrict__ XR1,
    const float* __restrict__ att1,
    const int* __restrict__ cnt1, const int* __restrict__ srcs1,
    float scale1,
    const float* __restrict__ base, float* __restrict__ outp, int N)
{
    int d = blockIdx.x * 4 + (threadIdx.x >> 6);
    if (d >= N) return;
    int lane = threadIdx.x & 63;
    uint hl = (uint)(lane >> 5);
    uint sub = (uint)(lane & 31);
    uint sub16 = sub * 16u;

    float acc0[8], den0;
    gat_hop(XL0, XR0, att0, cnt0, srcs0, self0, d, lane, hl, sub, sub16, acc0, den0);

    float v[8];
    den0 += __shfl_xor(den0, 32);
    float s0 = scale0 / (den0 + 1e-16f);
    if (cnt1) {
        float acc1[8], den1;
        gat_hop(XL1, XR1, att1, cnt1, srcs1, 0, d, lane, hl, sub, sub16, acc1, den1);
        den1 += __shfl_xor(den1, 32);
        float s1 = scale1 / (den1 + 1e-16f);
#pragma unroll
        for (int j = 0; j < 8; j++) v[j] = acc0[j] * s0 + acc1[j] * s1;
    } else {
#pragma unroll
        for (int j = 0; j < 8; j++) v[j] = acc0[j] * s0;
    }
#pragma unroll
    for (int j = 0; j < 8; j++) {
        v[j] += __shfl_xor(v[j], 8);
        v[j] += __shfl_xor(v[j], 16);
        v[j] += __shfl_xor(v[j], 32);
    }
    if (lane < 8) {
        float* dst = outp + (size_t)d * 64 + lane * 8;
        float4 w0 = {v[0], v[1], v[2], v[3]};
        float4 w1 = {v[4], v[5], v[6], v[7]};
        if (base) {
            float4 b0 = *(const float4*)(base + (size_t)d * 64 + lane * 8);
            float4 b1 = *(const float4*)(base + (size_t)d * 64 + lane * 8 + 4);
            w0.x += b0.x; w0.y += b0.y; w0.z += b0.z; w0.w += b0.w;
            w1.x += b1.x; w1.y += b1.y; w1.z += b1.z; w1.w += b1.w;
        }
        *(float4*)dst = w0;
        *(float4*)(dst + 4) = w1;
    }
}

// ---------- launch ----------
extern "C" void kernel_launch(void* const* d_in, const int* in_sizes, int n_in,
                              void* d_out, int out_size, void* d_ws, size_t ws_size,
                              hipStream_t stream)
{
    const float* x    = (const float*)d_in[0];
    const float* Wl0  = (const float*)d_in[1];
    const float* Wr0  = (const float*)d_in[2];
    const float* att0 = (const float*)d_in[3];
    const float* Wl1  = (const float*)d_in[4];
    const float* Wr1  = (const float*)d_in[5];
    const float* att1 = (const float*)d_in[6];
    const int* ei1 = (const int*)d_in[7];
    const int* ei2 = (const int*)d_in[8];

    const int N  = in_sizes[0] / 256;
    const int E1 = in_sizes[7] / 2;
    const int E2 = in_sizes[8] / 2;
    const int Mpad = ((N + 127) / 128) * 128;
    const size_t NB = (size_t)N * 256;

    // workspace layout
    char* ws = (char*)d_ws;
    size_t off = 0;
    ushort* Xb  = (ushort*)(ws + off); off += (size_t)Mpad * 256 * sizeof(ushort);
    ushort* Wt  = (ushort*)(ws + off); off += (size_t)1024 * 256 * sizeof(ushort);
    int* cnt0   = (int*)(ws + off);    off += (size_t)N * sizeof(int);
    int* cnt1   = (int*)(ws + off);    off += (size_t)N * sizeof(int);
    int* srcs0  = (int*)(ws + off);    off += (size_t)N * CAP * sizeof(int);
    int* srcs1  = (int*)(ws + off);    off += (size_t)N * CAP * sizeof(int);
    ushort* XP  = (ushort*)(ws + off);
    size_t need_mega = off + 4 * NB * sizeof(ushort);   // ~148 MB
    const bool mega = (ws_size >= need_mega);
    float* outf = (float*)d_out;

    const int BX = Mpad / 8;
    int prep_blocks = BX + 1024 + (N + 255) / 256;
    prep<<<prep_blocks, 256, 0, stream>>>(x, Xb, N, Mpad, Wl0, Wr0, Wl1, Wr1,
                                          Wt, cnt0, cnt1);
    const int SB = (E1 + E2 + 255) / 256;
    csr_scatter2<<<SB, 256, 0, stream>>>(
        ei1, ei2, cnt0, srcs0, cnt1, srcs1, E1, E2);

    int aggblk = (N + 3) / 4;
    if (mega) {
        gemm_mfma<<<dim3(8, Mpad / 128), 256, 0, stream>>>(Xb, Wt, XP, N);
        gat_fused<<<aggblk, 256, 0, stream>>>(
            XP, XP + NB, att0, cnt0, srcs0, 1, 0.25f,
            XP + 2 * NB, XP + 3 * NB, att1, cnt1, srcs1, 0.125f,
            nullptr, outf, N);
    } else {
        gemm_mfma<<<dim3(4, Mpad / 128), 256, 0, stream>>>(Xb, Wt, XP, N);
        gat_fused<<<aggblk, 256, 0, stream>>>(
            XP, XP + NB, att0, cnt0, srcs0, 1, 0.25f,
            nullptr, nullptr, nullptr, nullptr, nullptr, 0.f,
            nullptr, outf, N);
        gemm_mfma<<<dim3(4, Mpad / 128), 256, 0, stream>>>(Xb, Wt + 512 * 256, XP, N);
        gat_fused<<<aggblk, 256, 0, stream>>>(
            XP, XP + NB, att1, cnt1, srcs1, 0, 0.125f,
            nullptr, nullptr, nullptr, nullptr, nullptr, 0.f,
            outf, outf, N);
    }
}